// Round 6
// baseline (357.279 us; speedup 1.0000x reference)
//
#include <hip/hip_runtime.h>

typedef unsigned short u16;
typedef unsigned int   u32;
typedef short bf16x8 __attribute__((ext_vector_type(8)));
typedef float f32x4  __attribute__((ext_vector_type(4)));

#define BG    128      // graphs
#define NN    128      // nodes per graph
#define MS    16       // samples
#define KP    8        // pearl_k
#define HM    16       // mlp hidden
#define DP    64       // pe dims
#define NSUM  16384    // BG*NN
#define NE    262144   // edges
#define SITES 2048     // NN*MS

// R3: inputs f32, output f32. Intermediates bf16.
// R5: mm kernels on MFMA 16x16x32 bf16.
// R6: gathers m-sliced; h1/h2 stored transposed [m][node][*] so each XCD's
//     L2 holds its two 2.1MB slices (blockIdx%16 -> m, %8 -> XCD round-robin).

__device__ __forceinline__ float blo(u32 u){ union{u32 i; float f;} v; v.i=u<<16; return v.f; }
__device__ __forceinline__ float bhi(u32 u){ union{u32 i; float f;} v; v.i=u&0xffff0000u; return v.f; }
__device__ __forceinline__ u16  f2b(float f){ union{float f; u32 i;} v; v.f=f; u32 x=v.i; x += 0x7fffu + ((x>>16)&1u); return (u16)(x>>16); }
__device__ __forceinline__ u32  pk2(float a, float b){ return (u32)f2b(a) | ((u32)f2b(b)<<16); }

#define MFMA16(a,b,c) __builtin_amdgcn_mfma_f32_16x16x32_bf16(a,b,c,0,0,0)

__device__ __forceinline__ bf16x8 bfragW(const float* __restrict__ W, int nrows,
                                         int k0, int nb, int col, int quad){
  bf16x8 f;
  #pragma unroll
  for(int j=0;j<8;++j){
    int k = k0 + quad*8 + j;
    float v = (k < nrows) ? W[k*DP + nb + col] : 0.f;
    f[j] = (short)f2b(v);
  }
  return f;
}
__device__ __forceinline__ bf16x8 afragT(const float* tp){
  float4 v0 = *(const float4*)tp;
  float4 v1 = *(const float4*)(tp+4);
  bf16x8 a;
  a[0]=(short)f2b(v0.x); a[1]=(short)f2b(v0.y); a[2]=(short)f2b(v0.z); a[3]=(short)f2b(v0.w);
  a[4]=(short)f2b(v1.x); a[5]=(short)f2b(v1.y); a[6]=(short)f2b(v1.z); a[7]=(short)f2b(v1.w);
  return a;
}

// ---------------------------------------------------------------------------
// K1: per-graph polynomial filter + MLP over k + BN + ReLU.
// h1 written TRANSPOSED: h1T[m][node][c] (32B chunk per (site)).
// ---------------------------------------------------------------------------
__global__ __launch_bounds__(256) void k_poly(
    const float* __restrict__ lap, const float* __restrict__ W0, const float* __restrict__ mlpW,
    const float* __restrict__ bng, const float* __restrict__ bnb, u16* __restrict__ h1T)
{
  __shared__ float Wbuf[2][SITES];   // 16 KB
  __shared__ float mlpWS[KP*HM];
  __shared__ float red[4][32];
  __shared__ float stat[32];
  __shared__ float ssc[HM], ssh[HM];

  const int b = blockIdx.x, t = threadIdx.x;
  for (int i=t; i<SITES; i+=256) Wbuf[0][i] = W0[(size_t)b*SITES+i];
  if (t < KP*HM) mlpWS[t] = mlpW[t];
  __syncthreads();

  const int n = t>>1, m0 = (t&1)*8;
  float h[8][16];
  {
    float mw[16];
    #pragma unroll
    for(int c=0;c<16;++c) mw[c]=mlpWS[c];
    #pragma unroll
    for(int si=0;si<8;++si){
      float f0 = Wbuf[0][n*MS+m0+si];
      #pragma unroll
      for(int c=0;c<16;++c) h[si][c] = f0*mw[c];
    }
  }
  int cur=0;
  const float* lgf = lap + (size_t)b*NN*NN + (size_t)n*NN;
  for(int k=1;k<KP;++k){
    float acc[8];
    #pragma unroll
    for(int si=0;si<8;++si) acc[si]=0.f;
    const float* wb = &Wbuf[cur][m0];
    for(int j=0;j<NN;j+=2){
      float2 lv = *(const float2*)&lgf[j];
      float a0 = lv.x, a1 = lv.y;
      float4 w00 = *(const float4*)&wb[j*MS];
      float4 w01 = *(const float4*)&wb[j*MS+4];
      float4 w10 = *(const float4*)&wb[(j+1)*MS];
      float4 w11 = *(const float4*)&wb[(j+1)*MS+4];
      acc[0]+=a0*w00.x; acc[1]+=a0*w00.y; acc[2]+=a0*w00.z; acc[3]+=a0*w00.w;
      acc[4]+=a0*w01.x; acc[5]+=a0*w01.y; acc[6]+=a0*w01.z; acc[7]+=a0*w01.w;
      acc[0]+=a1*w10.x; acc[1]+=a1*w10.y; acc[2]+=a1*w10.z; acc[3]+=a1*w10.w;
      acc[4]+=a1*w11.x; acc[5]+=a1*w11.y; acc[6]+=a1*w11.z; acc[7]+=a1*w11.w;
    }
    __syncthreads();
    {
      float* wn = &Wbuf[cur^1][n*MS+m0];
      #pragma unroll
      for(int si=0;si<8;++si) wn[si]=acc[si];
      float mw[16];
      #pragma unroll
      for(int c=0;c<16;++c) mw[c]=mlpWS[k*16+c];
      #pragma unroll
      for(int si=0;si<8;++si){
        #pragma unroll
        for(int c=0;c<16;++c) h[si][c] += acc[si]*mw[c];
      }
    }
    __syncthreads();
    cur ^= 1;
  }
  float sum[16], sq[16];
  #pragma unroll
  for(int c=0;c<16;++c){ sum[c]=0.f; sq[c]=0.f; }
  #pragma unroll
  for(int si=0;si<8;++si){
    #pragma unroll
    for(int c=0;c<16;++c){ float v=h[si][c]; sum[c]+=v; sq[c]+=v*v; }
  }
  #pragma unroll
  for(int d=1;d<64;d<<=1){
    #pragma unroll
    for(int c=0;c<16;++c){ sum[c]+=__shfl_xor(sum[c],d,64); sq[c]+=__shfl_xor(sq[c],d,64); }
  }
  const int lane=t&63, wid=t>>6;
  if(lane==0){
    #pragma unroll
    for(int c=0;c<16;++c){ red[wid][c]=sum[c]; red[wid][16+c]=sq[c]; }
  }
  __syncthreads();
  if(t<32) stat[t]=red[0][t]+red[1][t]+red[2][t]+red[3][t];
  __syncthreads();
  if(t<16){
    float mu  = stat[t]*(1.f/SITES);
    float var = stat[16+t]*(1.f/SITES) - mu*mu;
    float sc  = bng[t] * rsqrtf(var + 1e-5f);
    ssc[t]=sc; ssh[t]=bnb[t] - mu*sc;
  }
  __syncthreads();
  {
    const int node = b*NN + n;
    float sc[16], sh[16];
    #pragma unroll
    for(int c=0;c<16;++c){ sc[c]=ssc[c]; sh[c]=ssh[c]; }
    #pragma unroll
    for(int si=0;si<8;++si){
      float r[16];
      #pragma unroll
      for(int c=0;c<16;++c) r[c]=fmaxf(h[si][c]*sc[c]+sh[c], 0.f);
      uint4 A, Bv;
      A.x =pk2(r[0],r[1]);   A.y =pk2(r[2],r[3]);   A.z =pk2(r[4],r[5]);   A.w =pk2(r[6],r[7]);
      Bv.x=pk2(r[8],r[9]);   Bv.y=pk2(r[10],r[11]); Bv.z=pk2(r[12],r[13]); Bv.w=pk2(r[14],r[15]);
      u16* o = h1T + ((size_t)(m0+si)*NSUM + node)*HM;
      *(uint4*)o     = A;
      *(uint4*)(o+8) = Bv;
    }
  }
}

// --------------------------- CSR build (by dst) ----------------------------
__global__ void k_hist(const int* __restrict__ dst, int* __restrict__ cnt){
  int e = blockIdx.x*256 + threadIdx.x;
  atomicAdd(&cnt[dst[e]], 1);
}

__global__ void k_scan(const int* __restrict__ cnt, int* __restrict__ off, int* __restrict__ wpos){
  __shared__ int ps[256];
  const int t = threadIdx.x, PER = NSUM/256;
  int s=0;
  for(int i=0;i<PER;++i) s += cnt[t*PER+i];
  ps[t]=s; __syncthreads();
  for(int d=1; d<256; d<<=1){
    int v = (t>=d) ? ps[t-d] : 0;
    __syncthreads();
    ps[t] += v;
    __syncthreads();
  }
  int run = (t==0) ? 0 : ps[t-1];
  for(int i=0;i<PER;++i){
    int idx=t*PER+i;
    off[idx]=run; wpos[idx]=run;
    run += cnt[idx];
  }
  if(t==255) off[NSUM]=run;
}

__global__ void k_scatter(const int* __restrict__ srcI, const int* __restrict__ dstI,
                          int* __restrict__ wpos, int* __restrict__ srcs){
  int e = blockIdx.x*256 + threadIdx.x;
  int p = atomicAdd(&wpos[dstI[e]], 1);
  srcs[p] = srcI[e];
}

// ---------------------------------------------------------------------------
// K4a: GIN-1 aggregate, m-sliced. m = blockIdx%16 (XCD-pinned slice, 0.5MB).
// Wave: 8 edge-slots x 8 dwords (32B row-slice). 4 nodes/wave.
// z1 written row-major [node][m][c].
// ---------------------------------------------------------------------------
__global__ __launch_bounds__(256) void k_agg1(
  const u16* __restrict__ h1T, const float* __restrict__ eps1p,
  const int* __restrict__ off, const int* __restrict__ srcs, u16* __restrict__ z1)
{
  const int t=threadIdx.x, l=t&63, w=t>>6;
  const int m = blockIdx.x & 15, g = blockIdx.x >> 4;
  const float epe = 1.f + eps1p[0];
  const u16* __restrict__ base = h1T + (size_t)m*NSUM*HM;
  const int slot = l>>3, dw = l&7;
  for(int ni=0;ni<4;++ni){
    const int node = g*16 + w*4 + ni;
    float a0, a1;
    {
      u32 x = *(const u32*)&base[(size_t)node*HM + dw*2];
      float s = (slot==0) ? epe : 0.f;
      a0 = s*blo(x); a1 = s*bhi(x);
    }
    const int e1 = off[node+1];
    int e = off[node] + slot;
    for(; e+16<=e1; e+=16){
      int s0=srcs[e], s1=srcs[e+8];
      u32 x0=*(const u32*)&base[(size_t)s0*HM + dw*2];
      u32 x1=*(const u32*)&base[(size_t)s1*HM + dw*2];
      a0+=blo(x0); a1+=bhi(x0); a0+=blo(x1); a1+=bhi(x1);
    }
    for(; e<e1; e+=8){
      u32 x=*(const u32*)&base[(size_t)srcs[e]*HM + dw*2];
      a0+=blo(x); a1+=bhi(x);
    }
    a0 += __shfl_xor(a0, 8,64); a1 += __shfl_xor(a1, 8,64);
    a0 += __shfl_xor(a0,16,64); a1 += __shfl_xor(a1,16,64);
    a0 += __shfl_xor(a0,32,64); a1 += __shfl_xor(a1,32,64);
    if(l<8)
      *(u32*)&z1[(size_t)node*256 + m*HM + dw*2] = pk2(a0,a1);
  }
}

// ---------------------------------------------------------------------------
// K5a: GIN-2 aggregate, m-sliced. m slice = 2.1MB, 2 slices/XCD in L2.
// Wave: 2 edge-slots x 32 dwords (128B row-slice), 4-deep batch. 4 nodes/wave.
// z2 written row-major [node][m][d].
// ---------------------------------------------------------------------------
__global__ __launch_bounds__(256) void k_agg2(
  const u16* __restrict__ h2T, const float* __restrict__ eps2p,
  const int* __restrict__ off, const int* __restrict__ srcs, u16* __restrict__ z2)
{
  const int t=threadIdx.x, l=t&63, w=t>>6;
  const int m = blockIdx.x & 15, g = blockIdx.x >> 4;
  const float epe = 1.f + eps2p[0];
  const u16* __restrict__ base = h2T + (size_t)m*NSUM*DP;
  const int slot = l>>5, dw = l&31;
  for(int ni=0;ni<4;++ni){
    const int node = g*16 + w*4 + ni;
    float a0, a1;
    {
      u32 x = *(const u32*)&base[(size_t)node*DP + dw*2];
      float s = (slot==0) ? epe : 0.f;
      a0 = s*blo(x); a1 = s*bhi(x);
    }
    const int e1 = off[node+1];
    int e = off[node] + slot;
    for(; e+8<=e1; e+=8){
      int s0=srcs[e], s1=srcs[e+2], s2=srcs[e+4], s3=srcs[e+6];
      u32 x0=*(const u32*)&base[(size_t)s0*DP + dw*2];
      u32 x1=*(const u32*)&base[(size_t)s1*DP + dw*2];
      u32 x2=*(const u32*)&base[(size_t)s2*DP + dw*2];
      u32 x3=*(const u32*)&base[(size_t)s3*DP + dw*2];
      a0+=blo(x0); a1+=bhi(x0); a0+=blo(x1); a1+=bhi(x1);
      a0+=blo(x2); a1+=bhi(x2); a0+=blo(x3); a1+=bhi(x3);
    }
    for(; e<e1; e+=2){
      u32 x=*(const u32*)&base[(size_t)srcs[e]*DP + dw*2];
      a0+=blo(x); a1+=bhi(x);
    }
    a0 += __shfl_xor(a0,32,64);
    a1 += __shfl_xor(a1,32,64);
    if(l<32)
      *(u32*)&z2[(size_t)node*1024 + m*DP + dw*2] = pk2(a0,a1);
  }
}

// ---------------------------------------------------------------------------
// K4b: GIN-1 MLP via MFMA; writes h2 TRANSPOSED h2T[m][node][d].
// ---------------------------------------------------------------------------
__global__ __launch_bounds__(256) void k_mm1(
  const u16* __restrict__ z1, const float* __restrict__ W1a, const float* __restrict__ b1a,
  const float* __restrict__ W1b, const float* __restrict__ b1b, u16* __restrict__ h2T)
{
  __shared__ float tS[4][16*68 + 4];        // 17.5 KB, per-wave slices
  const int t=threadIdx.x, l=t&63, w=t>>6;
  const int col=l&15, quad=l>>4;

  bf16x8 fa[4], fb[4][2];
  float bav[4], bbv[4];
  #pragma unroll
  for(int nt=0;nt<4;++nt){
    fa[nt]    = bfragW(W1a, HM, 0,  nt*16, col, quad);   // k>=16 zeroed
    fb[nt][0] = bfragW(W1b, DP, 0,  nt*16, col, quad);
    fb[nt][1] = bfragW(W1b, DP, 32, nt*16, col, quad);
    bav[nt] = b1a[nt*16+col];
    bbv[nt] = b1b[nt*16+col];
  }
  for(int ni=0;ni<2;++ni){
    const int node = blockIdx.x*8 + ni*4 + w;
    bf16x8 a0;
    #pragma unroll
    for(int j=0;j<8;++j) a0[j]=0;
    if (quad < 2) a0 = *(const bf16x8*)&z1[(size_t)node*256 + col*16 + quad*8];
    #pragma unroll
    for(int nt=0;nt<4;++nt){
      f32x4 c = {bav[nt], bav[nt], bav[nt], bav[nt]};
      c = MFMA16(a0, fa[nt], c);
      #pragma unroll
      for(int r=0;r<4;++r)
        tS[w][(quad*4+r)*68 + nt*16 + col] = fmaxf(c[r], 0.f);
    }
    bf16x8 ta0 = afragT(&tS[w][col*68 + quad*8]);
    bf16x8 ta1 = afragT(&tS[w][col*68 + 32 + quad*8]);
    #pragma unroll
    for(int nt=0;nt<4;++nt){
      f32x4 c = {bbv[nt], bbv[nt], bbv[nt], bbv[nt]};
      c = MFMA16(ta0, fb[nt][0], c);
      c = MFMA16(ta1, fb[nt][1], c);
      #pragma unroll
      for(int r=0;r<4;++r)
        h2T[((size_t)(quad*4+r)*NSUM + node)*DP + nt*16 + col] = f2b(fmaxf(c[r], 0.f));
    }
  }
}

// ---------------------------------------------------------------------------
// K5b: GIN-2 MLP via MFMA + ReLU + sum over M -> out f32 [NSUM,64].
// ---------------------------------------------------------------------------
__global__ __launch_bounds__(256) void k_mm2(
  const u16* __restrict__ z2, const float* __restrict__ W2a, const float* __restrict__ b2a,
  const float* __restrict__ W2b, const float* __restrict__ b2b, float* __restrict__ out)
{
  __shared__ float tS[4][16*68 + 4];
  const int t=threadIdx.x, l=t&63, w=t>>6;
  const int col=l&15, quad=l>>4;

  bf16x8 fa[4][2], fb[4][2];
  float bav[4], bbv[4];
  #pragma unroll
  for(int nt=0;nt<4;++nt){
    fa[nt][0] = bfragW(W2a, DP, 0,  nt*16, col, quad);
    fa[nt][1] = bfragW(W2a, DP, 32, nt*16, col, quad);
    fb[nt][0] = bfragW(W2b, DP, 0,  nt*16, col, quad);
    fb[nt][1] = bfragW(W2b, DP, 32, nt*16, col, quad);
    bav[nt] = b2a[nt*16+col];
    bbv[nt] = b2b[nt*16+col];
  }
  for(int ni=0;ni<2;++ni){
    const int node = blockIdx.x*8 + ni*4 + w;
    const u16* zrow = &z2[(size_t)node*1024];
    bf16x8 a0 = *(const bf16x8*)&zrow[col*64 + quad*8];
    bf16x8 a1 = *(const bf16x8*)&zrow[col*64 + quad*8 + 32];
    #pragma unroll
    for(int nt=0;nt<4;++nt){
      f32x4 c = {bav[nt], bav[nt], bav[nt], bav[nt]};
      c = MFMA16(a0, fa[nt][0], c);
      c = MFMA16(a1, fa[nt][1], c);
      #pragma unroll
      for(int r=0;r<4;++r)
        tS[w][(quad*4+r)*68 + nt*16 + col] = fmaxf(c[r], 0.f);
    }
    bf16x8 ta0 = afragT(&tS[w][col*68 + quad*8]);
    bf16x8 ta1 = afragT(&tS[w][col*68 + 32 + quad*8]);
    #pragma unroll
    for(int nt=0;nt<4;++nt){
      f32x4 c = {bbv[nt], bbv[nt], bbv[nt], bbv[nt]};
      c = MFMA16(ta0, fb[nt][0], c);
      c = MFMA16(ta1, fb[nt][1], c);
      float s = fmaxf(c[0],0.f)+fmaxf(c[1],0.f)+fmaxf(c[2],0.f)+fmaxf(c[3],0.f);
      s += __shfl_xor(s, 16, 64);
      s += __shfl_xor(s, 32, 64);
      if (quad == 0)
        out[(size_t)node*64 + nt*16 + col] = s;
    }
  }
}

extern "C" void kernel_launch(void* const* d_in, const int* in_sizes, int n_in,
                              void* d_out, int out_size, void* d_ws, size_t ws_size,
                              hipStream_t stream)
{
  (void)in_sizes; (void)n_in; (void)out_size; (void)ws_size;
  const float* lap  = (const float*)d_in[0];
  const float* W0   = (const float*)d_in[1];
  const float* mlpW = (const float*)d_in[2];
  // d_in[3] = mlp_b: cancels inside BatchNorm (pure mean shift)
  const float* bng  = (const float*)d_in[4];
  const float* bnb  = (const float*)d_in[5];
  const float* eps1 = (const float*)d_in[6];
  const float* W1a  = (const float*)d_in[7];
  const float* b1a  = (const float*)d_in[8];
  const float* W1b  = (const float*)d_in[9];
  const float* b1b  = (const float*)d_in[10];
  const float* eps2 = (const float*)d_in[11];
  const float* W2a  = (const float*)d_in[12];
  const float* b2a  = (const float*)d_in[13];
  const float* W2b  = (const float*)d_in[14];
  const float* b2b  = (const float*)d_in[15];
  const int*   ei   = (const int*)d_in[16];
  const int* srcI = ei;
  const int* dstI = ei + NE;

  char* ws = (char*)d_ws;
  u16* h1T  = (u16*)(ws);                    //  8,388,608 B  [16][16384][16]
  u16* z1   = (u16*)(ws + 8388608);          //  8,388,608 B  [16384][16][16]
  u16* h2T  = (u16*)(ws + 16777216);         // 33,554,432 B  [16][16384][64]
  u16* z2   = (u16*)(ws + 50331648);         // 33,554,432 B  [16384][16][64]
  int* cnt  = (int*)(ws + 83886080);         //     65,536 B
  int* offA = (int*)(ws + 83951616);         //     65,792 B
  int* wpos = (int*)(ws + 84017408);         //     65,536 B
  int* srcs = (int*)(ws + 84082944);         //  1,048,576 B  (end 85,131,520)

  hipMemsetAsync(cnt, 0, NSUM*sizeof(int), stream);
  k_poly   <<<BG,      256, 0, stream>>>(lap, W0, mlpW, bng, bnb, h1T);
  k_hist   <<<NE/256,  256, 0, stream>>>(dstI, cnt);
  k_scan   <<<1,       256, 0, stream>>>(cnt, offA, wpos);
  k_scatter<<<NE/256,  256, 0, stream>>>(srcI, dstI, wpos, srcs);
  k_agg1   <<<NSUM,    256, 0, stream>>>(h1T, eps1, offA, srcs, z1);
  k_mm1    <<<NSUM/8,  256, 0, stream>>>(z1, W1a, b1a, W1b, b1b, h2T);
  k_agg2   <<<NSUM,    256, 0, stream>>>(h2T, eps2, offA, srcs, z2);
  k_mm2    <<<NSUM/8,  256, 0, stream>>>(z2, W2a, b2a, W2b, b2b, (float*)d_out);
}

// Round 7
// 334.720 us; speedup vs baseline: 1.0674x; 1.0674x over previous
//
#include <hip/hip_runtime.h>

typedef unsigned short u16;
typedef unsigned int   u32;
typedef short bf16x8 __attribute__((ext_vector_type(8)));
typedef float f32x4  __attribute__((ext_vector_type(4)));

#define BG    128      // graphs
#define NN    128      // nodes per graph
#define MS    16       // samples
#define KP    8        // pearl_k
#define HM    16       // mlp hidden
#define DP    64       // pe dims
#define NSUM  16384    // BG*NN
#define NE    262144   // edges
#define SITES 2048     // NN*MS

// R3: inputs f32, output f32. Intermediates bf16.
// R5: mm kernels on MFMA 16x16x32 bf16.
// R6: m-sliced gathers (FETCH 248->57MB proven) but dword loads -> issue-bound.
// R7: m-sliced + fat loads: 8 edges/wave-inst via dwordx4 (agg2), 16 via
//     dwordx2 (agg1); cross-slot shfl combine.

__device__ __forceinline__ float blo(u32 u){ union{u32 i; float f;} v; v.i=u<<16; return v.f; }
__device__ __forceinline__ float bhi(u32 u){ union{u32 i; float f;} v; v.i=u&0xffff0000u; return v.f; }
__device__ __forceinline__ u16  f2b(float f){ union{float f; u32 i;} v; v.f=f; u32 x=v.i; x += 0x7fffu + ((x>>16)&1u); return (u16)(x>>16); }
__device__ __forceinline__ u32  pk2(float a, float b){ return (u32)f2b(a) | ((u32)f2b(b)<<16); }

__device__ __forceinline__ void acc8(float* a, uint4 x){
  a[0]+=blo(x.x); a[1]+=bhi(x.x); a[2]+=blo(x.y); a[3]+=bhi(x.y);
  a[4]+=blo(x.z); a[5]+=bhi(x.z); a[6]+=blo(x.w); a[7]+=bhi(x.w);
}
__device__ __forceinline__ void acc4(float* a, uint2 x){
  a[0]+=blo(x.x); a[1]+=bhi(x.x); a[2]+=blo(x.y); a[3]+=bhi(x.y);
}

#define MFMA16(a,b,c) __builtin_amdgcn_mfma_f32_16x16x32_bf16(a,b,c,0,0,0)

__device__ __forceinline__ bf16x8 bfragW(const float* __restrict__ W, int nrows,
                                         int k0, int nb, int col, int quad){
  bf16x8 f;
  #pragma unroll
  for(int j=0;j<8;++j){
    int k = k0 + quad*8 + j;
    float v = (k < nrows) ? W[k*DP + nb + col] : 0.f;
    f[j] = (short)f2b(v);
  }
  return f;
}
__device__ __forceinline__ bf16x8 afragT(const float* tp){
  float4 v0 = *(const float4*)tp;
  float4 v1 = *(const float4*)(tp+4);
  bf16x8 a;
  a[0]=(short)f2b(v0.x); a[1]=(short)f2b(v0.y); a[2]=(short)f2b(v0.z); a[3]=(short)f2b(v0.w);
  a[4]=(short)f2b(v1.x); a[5]=(short)f2b(v1.y); a[6]=(short)f2b(v1.z); a[7]=(short)f2b(v1.w);
  return a;
}

// ---------------------------------------------------------------------------
// K1: per-graph polynomial filter + MLP over k + BN + ReLU.
// h1 written TRANSPOSED: h1T[m][node][c].
// ---------------------------------------------------------------------------
__global__ __launch_bounds__(256) void k_poly(
    const float* __restrict__ lap, const float* __restrict__ W0, const float* __restrict__ mlpW,
    const float* __restrict__ bng, const float* __restrict__ bnb, u16* __restrict__ h1T)
{
  __shared__ float Wbuf[2][SITES];   // 16 KB
  __shared__ float mlpWS[KP*HM];
  __shared__ float red[4][32];
  __shared__ float stat[32];
  __shared__ float ssc[HM], ssh[HM];

  const int b = blockIdx.x, t = threadIdx.x;
  for (int i=t; i<SITES; i+=256) Wbuf[0][i] = W0[(size_t)b*SITES+i];
  if (t < KP*HM) mlpWS[t] = mlpW[t];
  __syncthreads();

  const int n = t>>1, m0 = (t&1)*8;
  float h[8][16];
  {
    float mw[16];
    #pragma unroll
    for(int c=0;c<16;++c) mw[c]=mlpWS[c];
    #pragma unroll
    for(int si=0;si<8;++si){
      float f0 = Wbuf[0][n*MS+m0+si];
      #pragma unroll
      for(int c=0;c<16;++c) h[si][c] = f0*mw[c];
    }
  }
  int cur=0;
  const float* lgf = lap + (size_t)b*NN*NN + (size_t)n*NN;
  for(int k=1;k<KP;++k){
    float acc[8];
    #pragma unroll
    for(int si=0;si<8;++si) acc[si]=0.f;
    const float* wb = &Wbuf[cur][m0];
    for(int j=0;j<NN;j+=2){
      float2 lv = *(const float2*)&lgf[j];
      float a0 = lv.x, a1 = lv.y;
      float4 w00 = *(const float4*)&wb[j*MS];
      float4 w01 = *(const float4*)&wb[j*MS+4];
      float4 w10 = *(const float4*)&wb[(j+1)*MS];
      float4 w11 = *(const float4*)&wb[(j+1)*MS+4];
      acc[0]+=a0*w00.x; acc[1]+=a0*w00.y; acc[2]+=a0*w00.z; acc[3]+=a0*w00.w;
      acc[4]+=a0*w01.x; acc[5]+=a0*w01.y; acc[6]+=a0*w01.z; acc[7]+=a0*w01.w;
      acc[0]+=a1*w10.x; acc[1]+=a1*w10.y; acc[2]+=a1*w10.z; acc[3]+=a1*w10.w;
      acc[4]+=a1*w11.x; acc[5]+=a1*w11.y; acc[6]+=a1*w11.z; acc[7]+=a1*w11.w;
    }
    __syncthreads();
    {
      float* wn = &Wbuf[cur^1][n*MS+m0];
      #pragma unroll
      for(int si=0;si<8;++si) wn[si]=acc[si];
      float mw[16];
      #pragma unroll
      for(int c=0;c<16;++c) mw[c]=mlpWS[k*16+c];
      #pragma unroll
      for(int si=0;si<8;++si){
        #pragma unroll
        for(int c=0;c<16;++c) h[si][c] += acc[si]*mw[c];
      }
    }
    __syncthreads();
    cur ^= 1;
  }
  float sum[16], sq[16];
  #pragma unroll
  for(int c=0;c<16;++c){ sum[c]=0.f; sq[c]=0.f; }
  #pragma unroll
  for(int si=0;si<8;++si){
    #pragma unroll
    for(int c=0;c<16;++c){ float v=h[si][c]; sum[c]+=v; sq[c]+=v*v; }
  }
  #pragma unroll
  for(int d=1;d<64;d<<=1){
    #pragma unroll
    for(int c=0;c<16;++c){ sum[c]+=__shfl_xor(sum[c],d,64); sq[c]+=__shfl_xor(sq[c],d,64); }
  }
  const int lane=t&63, wid=t>>6;
  if(lane==0){
    #pragma unroll
    for(int c=0;c<16;++c){ red[wid][c]=sum[c]; red[wid][16+c]=sq[c]; }
  }
  __syncthreads();
  if(t<32) stat[t]=red[0][t]+red[1][t]+red[2][t]+red[3][t];
  __syncthreads();
  if(t<16){
    float mu  = stat[t]*(1.f/SITES);
    float var = stat[16+t]*(1.f/SITES) - mu*mu;
    float sc  = bng[t] * rsqrtf(var + 1e-5f);
    ssc[t]=sc; ssh[t]=bnb[t] - mu*sc;
  }
  __syncthreads();
  {
    const int node = b*NN + n;
    float sc[16], sh[16];
    #pragma unroll
    for(int c=0;c<16;++c){ sc[c]=ssc[c]; sh[c]=ssh[c]; }
    #pragma unroll
    for(int si=0;si<8;++si){
      float r[16];
      #pragma unroll
      for(int c=0;c<16;++c) r[c]=fmaxf(h[si][c]*sc[c]+sh[c], 0.f);
      uint4 A, Bv;
      A.x =pk2(r[0],r[1]);   A.y =pk2(r[2],r[3]);   A.z =pk2(r[4],r[5]);   A.w =pk2(r[6],r[7]);
      Bv.x=pk2(r[8],r[9]);   Bv.y=pk2(r[10],r[11]); Bv.z=pk2(r[12],r[13]); Bv.w=pk2(r[14],r[15]);
      u16* o = h1T + ((size_t)(m0+si)*NSUM + node)*HM;
      *(uint4*)o     = A;
      *(uint4*)(o+8) = Bv;
    }
  }
}

// --------------------------- CSR build (by dst) ----------------------------
__global__ void k_hist(const int* __restrict__ dst, int* __restrict__ cnt){
  int e = blockIdx.x*256 + threadIdx.x;
  atomicAdd(&cnt[dst[e]], 1);
}

__global__ void k_scan(const int* __restrict__ cnt, int* __restrict__ off, int* __restrict__ wpos){
  __shared__ int ps[256];
  const int t = threadIdx.x, PER = NSUM/256;
  int s=0;
  for(int i=0;i<PER;++i) s += cnt[t*PER+i];
  ps[t]=s; __syncthreads();
  for(int d=1; d<256; d<<=1){
    int v = (t>=d) ? ps[t-d] : 0;
    __syncthreads();
    ps[t] += v;
    __syncthreads();
  }
  int run = (t==0) ? 0 : ps[t-1];
  for(int i=0;i<PER;++i){
    int idx=t*PER+i;
    off[idx]=run; wpos[idx]=run;
    run += cnt[idx];
  }
  if(t==255) off[NSUM]=run;
}

__global__ void k_scatter(const int* __restrict__ srcI, const int* __restrict__ dstI,
                          int* __restrict__ wpos, int* __restrict__ srcs){
  int e = blockIdx.x*256 + threadIdx.x;
  int p = atomicAdd(&wpos[dstI[e]], 1);
  srcs[p] = srcI[e];
}

// ---------------------------------------------------------------------------
// K4a: GIN-1 aggregate, m-sliced + fat loads. Slice row = 32B.
// Lane l: edge-slot l>>2 (16 slots), 8B chunk l&2x2 -> dwordx2 per edge;
// one inst = 16 edges x 32B = 512B. Combine slots via shfl_xor 4/8/16/32.
// ---------------------------------------------------------------------------
__global__ __launch_bounds__(256) void k_agg1(
  const u16* __restrict__ h1T, const float* __restrict__ eps1p,
  const int* __restrict__ off, const int* __restrict__ srcs, u16* __restrict__ z1)
{
  const int t=threadIdx.x, l=t&63, w=t>>6;
  const int m = blockIdx.x & 15, g = blockIdx.x >> 4;
  const float epe = 1.f + eps1p[0];
  const u16* __restrict__ base = h1T + (size_t)m*NSUM*HM;
  const int slot = l>>2, q = l&3;
  for(int ni=0;ni<4;++ni){
    const int node = g*16 + w*4 + ni;
    float a[4];
    {
      uint2 x = *(const uint2*)&base[(size_t)node*HM + q*4];
      float s = (slot==0) ? epe : 0.f;
      a[0]=s*blo(x.x); a[1]=s*bhi(x.x); a[2]=s*blo(x.y); a[3]=s*bhi(x.y);
    }
    const int e1 = off[node+1];
    int e = off[node] + slot;
    for(; e+16 < e1; e += 32){
      int s0=srcs[e], s1=srcs[e+16];
      uint2 x0=*(const uint2*)&base[(size_t)s0*HM + q*4];
      uint2 x1=*(const uint2*)&base[(size_t)s1*HM + q*4];
      acc4(a,x0); acc4(a,x1);
    }
    if(e < e1){
      uint2 x=*(const uint2*)&base[(size_t)srcs[e]*HM + q*4];
      acc4(a,x);
    }
    #pragma unroll
    for(int d=4;d<64;d<<=1){
      #pragma unroll
      for(int i=0;i<4;++i) a[i] += __shfl_xor(a[i], d, 64);
    }
    if(l<4){
      uint2 o; o.x=pk2(a[0],a[1]); o.y=pk2(a[2],a[3]);
      *(uint2*)&z1[(size_t)node*256 + m*HM + q*4] = o;
    }
  }
}

// ---------------------------------------------------------------------------
// K5a: GIN-2 aggregate, m-sliced + fat loads. Slice row = 128B.
// Lane l: edge-slot l>>3 (8 slots), 16B chunk l&7 -> dwordx4 per edge;
// one inst = 8 edges x 128B = 1KB. Combine slots via shfl_xor 8/16/32.
// ---------------------------------------------------------------------------
__global__ __launch_bounds__(256) void k_agg2(
  const u16* __restrict__ h2T, const float* __restrict__ eps2p,
  const int* __restrict__ off, const int* __restrict__ srcs, u16* __restrict__ z2)
{
  const int t=threadIdx.x, l=t&63, w=t>>6;
  const int m = blockIdx.x & 15, g = blockIdx.x >> 4;
  const float epe = 1.f + eps2p[0];
  const u16* __restrict__ base = h2T + (size_t)m*NSUM*DP;
  const int slot = l>>3, q = l&7;
  for(int ni=0;ni<4;++ni){
    const int node = g*16 + w*4 + ni;
    float a[8];
    {
      uint4 x = *(const uint4*)&base[(size_t)node*DP + q*8];
      float s = (slot==0) ? epe : 0.f;
      a[0]=s*blo(x.x); a[1]=s*bhi(x.x); a[2]=s*blo(x.y); a[3]=s*bhi(x.y);
      a[4]=s*blo(x.z); a[5]=s*bhi(x.z); a[6]=s*blo(x.w); a[7]=s*bhi(x.w);
    }
    const int e1 = off[node+1];
    int e = off[node] + slot;
    for(; e+8 < e1; e += 16){
      int s0=srcs[e], s1=srcs[e+8];
      uint4 x0=*(const uint4*)&base[(size_t)s0*DP + q*8];
      uint4 x1=*(const uint4*)&base[(size_t)s1*DP + q*8];
      acc8(a,x0); acc8(a,x1);
    }
    if(e < e1){
      uint4 x=*(const uint4*)&base[(size_t)srcs[e]*DP + q*8];
      acc8(a,x);
    }
    #pragma unroll
    for(int d=8;d<64;d<<=1){
      #pragma unroll
      for(int i=0;i<8;++i) a[i] += __shfl_xor(a[i], d, 64);
    }
    if(l<8){
      uint4 o;
      o.x=pk2(a[0],a[1]); o.y=pk2(a[2],a[3]); o.z=pk2(a[4],a[5]); o.w=pk2(a[6],a[7]);
      *(uint4*)&z2[(size_t)node*1024 + m*DP + q*8] = o;
    }
  }
}

// ---------------------------------------------------------------------------
// K4b: GIN-1 MLP via MFMA; writes h2 TRANSPOSED h2T[m][node][d].
// ---------------------------------------------------------------------------
__global__ __launch_bounds__(256) void k_mm1(
  const u16* __restrict__ z1, const float* __restrict__ W1a, const float* __restrict__ b1a,
  const float* __restrict__ W1b, const float* __restrict__ b1b, u16* __restrict__ h2T)
{
  __shared__ float tS[4][16*68 + 4];        // 17.5 KB, per-wave slices
  const int t=threadIdx.x, l=t&63, w=t>>6;
  const int col=l&15, quad=l>>4;

  bf16x8 fa[4], fb[4][2];
  float bav[4], bbv[4];
  #pragma unroll
  for(int nt=0;nt<4;++nt){
    fa[nt]    = bfragW(W1a, HM, 0,  nt*16, col, quad);   // k>=16 zeroed
    fb[nt][0] = bfragW(W1b, DP, 0,  nt*16, col, quad);
    fb[nt][1] = bfragW(W1b, DP, 32, nt*16, col, quad);
    bav[nt] = b1a[nt*16+col];
    bbv[nt] = b1b[nt*16+col];
  }
  for(int ni=0;ni<2;++ni){
    const int node = blockIdx.x*8 + ni*4 + w;
    bf16x8 a0;
    #pragma unroll
    for(int j=0;j<8;++j) a0[j]=0;
    if (quad < 2) a0 = *(const bf16x8*)&z1[(size_t)node*256 + col*16 + quad*8];
    #pragma unroll
    for(int nt=0;nt<4;++nt){
      f32x4 c = {bav[nt], bav[nt], bav[nt], bav[nt]};
      c = MFMA16(a0, fa[nt], c);
      #pragma unroll
      for(int r=0;r<4;++r)
        tS[w][(quad*4+r)*68 + nt*16 + col] = fmaxf(c[r], 0.f);
    }
    bf16x8 ta0 = afragT(&tS[w][col*68 + quad*8]);
    bf16x8 ta1 = afragT(&tS[w][col*68 + 32 + quad*8]);
    #pragma unroll
    for(int nt=0;nt<4;++nt){
      f32x4 c = {bbv[nt], bbv[nt], bbv[nt], bbv[nt]};
      c = MFMA16(ta0, fb[nt][0], c);
      c = MFMA16(ta1, fb[nt][1], c);
      #pragma unroll
      for(int r=0;r<4;++r)
        h2T[((size_t)(quad*4+r)*NSUM + node)*DP + nt*16 + col] = f2b(fmaxf(c[r], 0.f));
    }
  }
}

// ---------------------------------------------------------------------------
// K5b: GIN-2 MLP via MFMA + ReLU + sum over M -> out f32 [NSUM,64].
// ---------------------------------------------------------------------------
__global__ __launch_bounds__(256) void k_mm2(
  const u16* __restrict__ z2, const float* __restrict__ W2a, const float* __restrict__ b2a,
  const float* __restrict__ W2b, const float* __restrict__ b2b, float* __restrict__ out)
{
  __shared__ float tS[4][16*68 + 4];
  const int t=threadIdx.x, l=t&63, w=t>>6;
  const int col=l&15, quad=l>>4;

  bf16x8 fa[4][2], fb[4][2];
  float bav[4], bbv[4];
  #pragma unroll
  for(int nt=0;nt<4;++nt){
    fa[nt][0] = bfragW(W2a, DP, 0,  nt*16, col, quad);
    fa[nt][1] = bfragW(W2a, DP, 32, nt*16, col, quad);
    fb[nt][0] = bfragW(W2b, DP, 0,  nt*16, col, quad);
    fb[nt][1] = bfragW(W2b, DP, 32, nt*16, col, quad);
    bav[nt] = b2a[nt*16+col];
    bbv[nt] = b2b[nt*16+col];
  }
  for(int ni=0;ni<2;++ni){
    const int node = blockIdx.x*8 + ni*4 + w;
    const u16* zrow = &z2[(size_t)node*1024];
    bf16x8 a0 = *(const bf16x8*)&zrow[col*64 + quad*8];
    bf16x8 a1 = *(const bf16x8*)&zrow[col*64 + quad*8 + 32];
    #pragma unroll
    for(int nt=0;nt<4;++nt){
      f32x4 c = {bav[nt], bav[nt], bav[nt], bav[nt]};
      c = MFMA16(a0, fa[nt][0], c);
      c = MFMA16(a1, fa[nt][1], c);
      #pragma unroll
      for(int r=0;r<4;++r)
        tS[w][(quad*4+r)*68 + nt*16 + col] = fmaxf(c[r], 0.f);
    }
    bf16x8 ta0 = afragT(&tS[w][col*68 + quad*8]);
    bf16x8 ta1 = afragT(&tS[w][col*68 + 32 + quad*8]);
    #pragma unroll
    for(int nt=0;nt<4;++nt){
      f32x4 c = {bbv[nt], bbv[nt], bbv[nt], bbv[nt]};
      c = MFMA16(ta0, fb[nt][0], c);
      c = MFMA16(ta1, fb[nt][1], c);
      float s = fmaxf(c[0],0.f)+fmaxf(c[1],0.f)+fmaxf(c[2],0.f)+fmaxf(c[3],0.f);
      s += __shfl_xor(s, 16, 64);
      s += __shfl_xor(s, 32, 64);
      if (quad == 0)
        out[(size_t)node*64 + nt*16 + col] = s;
    }
  }
}

extern "C" void kernel_launch(void* const* d_in, const int* in_sizes, int n_in,
                              void* d_out, int out_size, void* d_ws, size_t ws_size,
                              hipStream_t stream)
{
  (void)in_sizes; (void)n_in; (void)out_size; (void)ws_size;
  const float* lap  = (const float*)d_in[0];
  const float* W0   = (const float*)d_in[1];
  const float* mlpW = (const float*)d_in[2];
  // d_in[3] = mlp_b: cancels inside BatchNorm (pure mean shift)
  const float* bng  = (const float*)d_in[4];
  const float* bnb  = (const float*)d_in[5];
  const float* eps1 = (const float*)d_in[6];
  const float* W1a  = (const float*)d_in[7];
  const float* b1a  = (const float*)d_in[8];
  const float* W1b  = (const float*)d_in[9];
  const float* b1b  = (const float*)d_in[10];
  const float* eps2 = (const float*)d_in[11];
  const float* W2a  = (const float*)d_in[12];
  const float* b2a  = (const float*)d_in[13];
  const float* W2b  = (const float*)d_in[14];
  const float* b2b  = (const float*)d_in[15];
  const int*   ei   = (const int*)d_in[16];
  const int* srcI = ei;
  const int* dstI = ei + NE;

  char* ws = (char*)d_ws;
  u16* h1T  = (u16*)(ws);                    //  8,388,608 B  [16][16384][16]
  u16* z1   = (u16*)(ws + 8388608);          //  8,388,608 B  [16384][16][16]
  u16* h2T  = (u16*)(ws + 16777216);         // 33,554,432 B  [16][16384][64]
  u16* z2   = (u16*)(ws + 50331648);         // 33,554,432 B  [16384][16][64]
  int* cnt  = (int*)(ws + 83886080);         //     65,536 B
  int* offA = (int*)(ws + 83951616);         //     65,792 B
  int* wpos = (int*)(ws + 84017408);         //     65,536 B
  int* srcs = (int*)(ws + 84082944);         //  1,048,576 B  (end 85,131,520)

  hipMemsetAsync(cnt, 0, NSUM*sizeof(int), stream);
  k_poly   <<<BG,      256, 0, stream>>>(lap, W0, mlpW, bng, bnb, h1T);
  k_hist   <<<NE/256,  256, 0, stream>>>(dstI, cnt);
  k_scan   <<<1,       256, 0, stream>>>(cnt, offA, wpos);
  k_scatter<<<NE/256,  256, 0, stream>>>(srcI, dstI, wpos, srcs);
  k_agg1   <<<NSUM,    256, 0, stream>>>(h1T, eps1, offA, srcs, z1);
  k_mm1    <<<NSUM/8,  256, 0, stream>>>(z1, W1a, b1a, W1b, b1b, h2T);
  k_agg2   <<<NSUM,    256, 0, stream>>>(h2T, eps2, offA, srcs, z2);
  k_mm2    <<<NSUM/8,  256, 0, stream>>>(z2, W2a, b2a, W2b, b2b, (float*)d_out);
}